// Round 1
// baseline (88.461 us; speedup 1.0000x reference)
//
#include <hip/hip_runtime.h>
#include <math.h>

#define WAVE 64
#define E    16            // elements per lane (4 x float4)
#define SPAN (WAVE * E)    // 1024 elements covered per wave
#define W    128           // window length
#define OUTS (SPAN - W)    // 896 outputs per wave

__global__ __launch_bounds__(256) void swmin_kernel(const float* __restrict__ x,
                                                    float* __restrict__ out,
                                                    int n) {
    const int wave_id = blockIdx.x * (blockDim.x / WAVE) + (threadIdx.x / WAVE);
    const int lane    = threadIdx.x & (WAVE - 1);
    const int base    = wave_id * OUTS - W;        // first element of this wave's range
    const int lbase   = base + lane * E;           // this lane's first element

    float b[E];

    // ---- load 4 x float4 (aligned: base/lbase are multiples of 4; N % 128 == 0) ----
#pragma unroll
    for (int k = 0; k < E / 4; ++k) {
        const int p = lbase + 4 * k;
        if (p >= 0 && p + 3 < n) {
            const float4 v = *reinterpret_cast<const float4*>(x + p);
            b[4 * k + 0] = v.x; b[4 * k + 1] = v.y;
            b[4 * k + 2] = v.z; b[4 * k + 3] = v.w;
        } else {
            b[4 * k + 0] = INFINITY; b[4 * k + 1] = INFINITY;
            b[4 * k + 2] = INFINITY; b[4 * k + 3] = INFINITY;
        }
    }

    // ---- doubling steps: b[j] = min(b[j], value at position-j-s) ----
    // sub-lane shifts s = 1,2,4,8: boundary entries come from prev lane via shfl_up(1)
#pragma unroll
    for (int s = 1; s < E; s <<= 1) {
        float t[E];
#pragma unroll
        for (int j = 0; j < s; ++j)
            t[j] = __shfl_up(b[E - s + j], 1);
#pragma unroll
        for (int j = E - 1; j >= s; --j)        // descending: in-place safe
            b[j] = fminf(b[j], b[j - s]);
#pragma unroll
        for (int j = 0; j < s; ++j)
            b[j] = fminf(b[j], t[j]);
    }
    // lane-multiple shifts s = 16, 32, 64  ->  shfl_up by 1, 2, 4 lanes
#pragma unroll
    for (int s = E; s <= W / 2; s <<= 1) {
        const int L = s / E;
        float t[E];
#pragma unroll
        for (int j = 0; j < E; ++j)
            t[j] = __shfl_up(b[j], L);
#pragma unroll
        for (int j = 0; j < E; ++j)
            b[j] = fminf(b[j], t[j]);
    }

    // ---- store: lanes 8..63 hold valid outputs (first 128 elems are halo) ----
    if (lane >= W / E) {
#pragma unroll
        for (int k = 0; k < E / 4; ++k) {
            const int p = lbase + 4 * k;
            if (p + 3 < n) {   // p >= 0 guaranteed for lane >= 8
                *reinterpret_cast<float4*>(out + p) =
                    make_float4(b[4 * k + 0], b[4 * k + 1], b[4 * k + 2], b[4 * k + 3]);
            }
        }
    }
}

extern "C" void kernel_launch(void* const* d_in, const int* in_sizes, int n_in,
                              void* d_out, int out_size, void* d_ws, size_t ws_size,
                              hipStream_t stream) {
    const float* x = (const float*)d_in[0];
    float* out     = (float*)d_out;
    const int n    = in_sizes[0];

    const int waves_per_block = 256 / WAVE;                       // 4
    const int total_waves     = (n + OUTS - 1) / OUTS;            // 9363 for N=8.4M
    const int blocks          = (total_waves + waves_per_block - 1) / waves_per_block;

    swmin_kernel<<<blocks, 256, 0, stream>>>(x, out, n);
}